// Round 5
// baseline (105.012 us; speedup 1.0000x reference)
//
#include <hip/hip_runtime.h>

// MultiAgentLinearLayer via bf16 MFMA, round 7: quarter-pipelined X staging.
// out[b,o] = sum_k W[agent[b],o,k]*x[b,k] + bias[agent[b],o]
// B=2048, I=O=512, 64 agents, fp32 in/out. Threshold 5.97e-2 permits bf16.
//
// Evidence trail: R4=104.6 (3-deep prime), R6=104.9 (6-deep prime, which
// first) -> prefetch depth saturated; R5 (8 waves/CU) = 113.9 -> structure
// matters; 32 waves/CU impossible (needs VGPR<=64). Residual theory: X
// staging (8 gather rounds + pack, barrier-bracketed) is serial-exposed.
// R7: pipeline staging against the K-loop inside the same waves:
//   stage quarters {[0,128),[256,384)} -> barrier -> K-iters 0..3 (these
//   read only those quarters) with the OTHER quarter-pair's gathers already
//   in flight (issued pre-barrier into regs) -> LDS-write them -> barrier ->
//   K-iters 4..7. Half the staging + its pack VALU hides under MFMA+W-drain;
//   first MFMA starts ~1.5us earlier. Same layout, same accumulation order
//   -> bitwise-identical output. +1 barrier, +16 VGPR (~110 total, <=128).
// Everything else = R4: 16 waves, kh-split + Rs(stride 17: unpadded is a
// 4-way conflict, audited), XCD swizzle, cvt_pk packing, nfrag guard,
// stride-520 Xs, 3-deep W prime.

constexpr int BATCH  = 2048;
constexpr int NAGENT = 64;
constexpr int IN_F   = 512;
constexpr int OUT_F  = 512;

constexpr int BN  = 128;        // block n-tile
constexpr int MCH = 64;         // m rows per chunk (count<=64 in practice)
constexpr int XS  = IN_F + 8;   // X LDS stride in bf16 elems (520)

typedef __attribute__((ext_vector_type(8))) short short8;     // bf16 A/B frag
typedef __attribute__((ext_vector_type(4))) float f32x4;      // fp32 C/D frag
typedef __attribute__((ext_vector_type(4))) unsigned int u32x4;
typedef __bf16 bf16x2 __attribute__((ext_vector_type(2)));

__device__ inline unsigned pk_bf(float lo, float hi) {
  bf16x2 v;
  v[0] = (__bf16)lo;
  v[1] = (__bf16)hi;
  return __builtin_bit_cast(unsigned, v);   // v_cvt_pk_bf16_f32, RNE
}

__global__ __launch_bounds__(1024, 4) void agent_linear_mfma7(
    const int*   __restrict__ which,
    const float* __restrict__ x,
    const float* __restrict__ weight,
    const float* __restrict__ bias,
    float*       __restrict__ out) {
  const int tid   = threadIdx.x;
  const int lane  = tid & 63;
  const int wid   = tid >> 6;        // 0..15
  const int w8    = wid & 7;         // n-wave within BN
  const int kh    = wid >> 3;        // k-half: 0 or 1

  // bid = (a&7) + 8*n + 32*(a>>3): agent a's 4 n-tiles all share bid%8
  const int bid   = blockIdx.x;      // 0..255
  const int agent = (bid & 7) | ((bid >> 5) << 3);
  const int obase = ((bid >> 3) & 3) * BN;

  __shared__ int rowlist_s[BATCH];                       // 8 KB
  __shared__ int wsum_s[16];
  __shared__ __align__(16) unsigned short Xs[MCH * XS];  // 65 KB bf16
  __shared__ float Rs[8][MCH][17];                       // 34 KB, k-half partials

  // ---- issue `which` load first (longest dependent chain) ----
  int2 v = ((const int2*)which)[tid];                    // 2 vals/thread

  const int nl = lane & 15;      // n within frag / m within A-frag
  const int kq = lane >> 4;      // k-quad 0..3

  const float* wp = weight + ((size_t)(agent * OUT_F + obase + w8 * 16 + nl)) * IN_F
                  + kh * 256 + kq * 8;

  // ---- prime 3-deep W prefetch (depth beyond 3 proven neutral R6) ----
  float4 pa[3], pb[3];
#pragma unroll
  for (int j = 0; j < 3; ++j) {
    pa[j] = *(const float4*)(wp + j * 32);
    pb[j] = *(const float4*)(wp + j * 32 + 4);
  }

  const float bv = bias[agent * OUT_F + obase + w8 * 16 + nl];

  // ---- stable compaction: rows with which[i]==agent, ascending ----
  int lc = (v.x == agent) + (v.y == agent);
  int s = lc;
#pragma unroll
  for (int off = 1; off < 64; off <<= 1) {
    int t = __shfl_up(s, off);
    if (lane >= off) s += t;
  }
  if (lane == 63) wsum_s[wid] = s;
  __syncthreads();
  int base = 0, count = 0;
#pragma unroll
  for (int w = 0; w < 16; ++w) {
    int ws = wsum_s[w];
    if (w < wid) base += ws;
    count += ws;
  }
  {
    int pos = base + s - lc;
    if (v.x == agent) rowlist_s[pos++] = 2 * tid;
    if (v.y == agent) rowlist_s[pos]   = 2 * tid + 1;
  }

  // Staging geometry: round t covers rows r = t*16 + wid (wave-uniform);
  // lanes 0..31 -> float4 cols base+0..31, lanes 32..63 -> base+64..95.
  // Quarter-pair A: col base 0  -> k elems [0,128) & [256,384)
  // Quarter-pair B: col base 32 -> k elems [128,256) & [384,512)
  const int cA = (lane & 31) + ((lane >> 5) << 6);
  const int cB = cA + 32;

  for (int m0 = 0; m0 < count; m0 += MCH) {
    const int mcount = min(MCH, count - m0);
    const int nfrag  = (mcount + 15) >> 4;   // live 16-row A-frags (1..4)

    __syncthreads();   // iter0: rowlist ready; later: prior chunk reads done

    // ---- stage quarter-pair A (4 rounds) ----
#pragma unroll
    for (int t = 0; t < 4; ++t) {
      int r = t * 16 + wid;
      if (r < mcount) {
        float4 xv = *(const float4*)(x + (size_t)rowlist_s[m0 + r] * IN_F + cA * 4);
        uint2 w2;
        w2.x = pk_bf(xv.x, xv.y);
        w2.y = pk_bf(xv.z, xv.w);
        *(uint2*)&Xs[r * XS + cA * 4] = w2;
      }
    }
    // ---- issue quarter-pair B gathers now; consumed after K phase 1 ----
    float4 sb[4];
#pragma unroll
    for (int t = 0; t < 4; ++t) {
      int r = t * 16 + wid;
      sb[t] = (r < mcount)
            ? *(const float4*)(x + (size_t)rowlist_s[m0 + r] * IN_F + cB * 4)
            : float4{0.f, 0.f, 0.f, 0.f};
    }
    __syncthreads();   // quarter-pair A visible

    f32x4 acc[4] = {{0.f,0.f,0.f,0.f},{0.f,0.f,0.f,0.f},
                    {0.f,0.f,0.f,0.f},{0.f,0.f,0.f,0.f}};
    const int kbase = kh * 256;

    // ---- K phase 1: k=0..3 (reads only quarter-pair A columns) ----
#pragma unroll
    for (int k = 0; k < 4; ++k) {
      float4 c0 = pa[k % 3], c1 = pb[k % 3];
      pa[k % 3] = *(const float4*)(wp + (k + 3) * 32);
      pb[k % 3] = *(const float4*)(wp + (k + 3) * 32 + 4);
      u32x4 q;
      q[0] = pk_bf(c0.x, c0.y); q[1] = pk_bf(c0.z, c0.w);
      q[2] = pk_bf(c1.x, c1.y); q[3] = pk_bf(c1.z, c1.w);
      short8 bfr = __builtin_bit_cast(short8, q);
#pragma unroll
      for (int i = 0; i < 4; ++i) {
        if (i < nfrag) {
          short8 af = *(const short8*)&Xs[(i * 16 + nl) * XS + kbase + k * 32 + kq * 8];
          acc[i] = __builtin_amdgcn_mfma_f32_16x16x32_bf16(af, bfr, acc[i], 0, 0, 0);
        }
      }
    }

    // ---- pack + write quarter-pair B (loads arrived during phase 1) ----
#pragma unroll
    for (int t = 0; t < 4; ++t) {
      int r = t * 16 + wid;
      if (r < mcount) {
        uint2 w2;
        w2.x = pk_bf(sb[t].x, sb[t].y);
        w2.y = pk_bf(sb[t].z, sb[t].w);
        *(uint2*)&Xs[r * XS + cB * 4] = w2;
      }
    }
    __syncthreads();   // quarter-pair B visible

    // ---- K phase 2: k=4..7 ----
#pragma unroll
    for (int k = 4; k < 8; ++k) {
      float4 c0 = pa[k % 3], c1 = pb[k % 3];
      if (k + 3 < 8) {
        pa[k % 3] = *(const float4*)(wp + (k + 3) * 32);
        pb[k % 3] = *(const float4*)(wp + (k + 3) * 32 + 4);
      }
      u32x4 q;
      q[0] = pk_bf(c0.x, c0.y); q[1] = pk_bf(c0.z, c0.w);
      q[2] = pk_bf(c1.x, c1.y); q[3] = pk_bf(c1.z, c1.w);
      short8 bfr = __builtin_bit_cast(short8, q);
#pragma unroll
      for (int i = 0; i < 4; ++i) {
        if (i < nfrag) {
          short8 af = *(const short8*)&Xs[(i * 16 + nl) * XS + kbase + k * 32 + kq * 8];
          acc[i] = __builtin_amdgcn_mfma_f32_16x16x32_bf16(af, bfr, acc[i], 0, 0, 0);
        }
      }
    }

    // ---- cross-k-half reduction: upper waves park partials in LDS ----
    if (kh == 1) {
#pragma unroll
      for (int i = 0; i < 4; ++i)
        if (i < nfrag)
#pragma unroll
          for (int r = 0; r < 4; ++r)
            Rs[w8][i * 16 + kq * 4 + r][nl] = acc[i][r];
    }
    __syncthreads();   // Rs ready

    // ---- epilogue by lower waves: D row=(lane>>4)*4+reg, col=lane&15 ----
    if (kh == 0) {
#pragma unroll
      for (int i = 0; i < 4; ++i) {
        if (i < nfrag) {
#pragma unroll
          for (int r = 0; r < 4; ++r) {
            int m = i * 16 + kq * 4 + r;
            if (m < mcount) {
              out[(size_t)rowlist_s[m0 + m] * OUT_F + obase + w8 * 16 + nl] =
                  acc[i][r] + Rs[w8][m][nl] + bv;
            }
          }
        }
      }
    }

    if (m0 + MCH < count) {   // re-prime for the (rare) next chunk; L2-hot
#pragma unroll
      for (int j = 0; j < 3; ++j) {
        pa[j] = *(const float4*)(wp + j * 32);
        pb[j] = *(const float4*)(wp + j * 32 + 4);
      }
    }
  }
}

extern "C" void kernel_launch(void* const* d_in, const int* in_sizes, int n_in,
                              void* d_out, int out_size, void* d_ws, size_t ws_size,
                              hipStream_t stream) {
  const int*   which = (const int*)d_in[0];
  const float* x     = (const float*)d_in[1];
  const float* w     = (const float*)d_in[2];
  const float* b     = (const float*)d_in[3];
  float*       out   = (float*)d_out;

  dim3 grid(OUT_F / BN * NAGENT);   // 256 blocks, 1 per CU (swizzled decode)
  agent_linear_mfma7<<<grid, dim3(1024), 0, stream>>>(which, x, w, b, out);
}